// Round 1
// baseline (4814.521 us; speedup 1.0000x reference)
//
#include <hip/hip_runtime.h>
#include <math.h>

constexpr int NB = 32;      // batches
constexpr int NP = 1024;    // points per batch
constexpr int NK = 10;      // k nearest (includes self)
constexpr int BN = NB * NP;
constexpr int NBCH = 8;     // batches per dist chunk

__device__ __forceinline__ float4 ld4(const float* p){ return *reinterpret_cast<const float4*>(p); }
__device__ __forceinline__ float2 ld2(const float* p){ return *reinterpret_cast<const float2*>(p); }
__device__ __forceinline__ void st4(float* p, float4 v){ *reinterpret_cast<float4*>(p) = v; }

// ---------------- sq norms of pos ----------------
__global__ __launch_bounds__(256) void k_sq_pos(const float* __restrict__ x, float* __restrict__ sq){
  int i = blockIdx.x*256 + threadIdx.x;
  float2 v = ld2(x + (size_t)2*i);
  sq[i] = v.x*v.x + v.y*v.y;
}

// ---------------- dist matrix, DIN=2 (layer 1) ----------------
__global__ __launch_bounds__(256) void k_dist2(const float* __restrict__ x,
    const float* __restrict__ sq, float* __restrict__ dist, int b0){
  int bz = blockIdx.z;
  int b = b0 + bz;
  int n0 = blockIdx.x*128, m0 = blockIdx.y*128;
  int ry = threadIdx.x>>4, rx = threadIdx.x&15;
  const float* xb = x + (size_t)b*NP*2;
  const float* sqb = sq + (size_t)b*NP;
  float2 av[8], bv[8]; float sn[8], sm[8];
#pragma unroll
  for (int k=0;k<8;++k){
    av[k] = ld2(xb + (size_t)(n0+ry*8+k)*2);
    bv[k] = ld2(xb + (size_t)(m0+rx*8+k)*2);
    sn[k] = sqb[n0+ry*8+k];
    sm[k] = sqb[m0+rx*8+k];
  }
  float* dbase = dist + ((size_t)bz*NP + n0 + ry*8)*NP + m0 + rx*8;
#pragma unroll
  for (int k=0;k<8;++k){
    float r[8];
#pragma unroll
    for (int l=0;l<8;++l){
      float dot = av[k].x*bv[l].x + av[k].y*bv[l].y;
      r[l] = (sn[k] + sm[l]) - 2.f*dot;
    }
    st4(dbase + (size_t)k*NP,     make_float4(r[0],r[1],r[2],r[3]));
    st4(dbase + (size_t)k*NP + 4, make_float4(r[4],r[5],r[6],r[7]));
  }
}

// ---------------- dist matrix, DIN in {64,128} ----------------
template<int DIN>
__global__ __launch_bounds__(256,2) void k_dist(const float* __restrict__ x,
    const float* __restrict__ sq, float* __restrict__ dist, int b0){
  constexpr int CH = 32, C4 = 8, STR = 9;   // 32-dim chunks, 8 f4 + 1 pad per row
  __shared__ float4 as_[128*STR];
  __shared__ float4 bs_[128*STR];
  int bz = blockIdx.z;
  int b = b0 + bz;
  int n0 = blockIdx.x*128, m0 = blockIdx.y*128;
  int ry = threadIdx.x>>4, rx = threadIdx.x&15;
  const float* xb = x + (size_t)b*NP*DIN;
  float acc[8][8];
#pragma unroll
  for (int k=0;k<8;++k)
#pragma unroll
    for (int l=0;l<8;++l) acc[k][l] = 0.f;
  for (int ch=0; ch<DIN/CH; ++ch){
    __syncthreads();
    for (int u=threadIdx.x; u<128*C4; u+=256){
      int r = u>>3, c = u&7;
      int sw = c ^ ((r>>3)&7);              // XOR swizzle: conflict-free b128 reads
      as_[r*STR + sw] = ld4(xb + (size_t)(n0+r)*DIN + ch*CH + 4*c);
      bs_[r*STR + sw] = ld4(xb + (size_t)(m0+r)*DIN + ch*CH + 4*c);
    }
    __syncthreads();
#pragma unroll
    for (int d4=0; d4<C4; ++d4){
      float4 a_[8], b_[8];
#pragma unroll
      for (int k=0;k<8;++k) a_[k] = as_[(ry*8+k)*STR + (d4 ^ (ry&7))];
#pragma unroll
      for (int l=0;l<8;++l) b_[l] = bs_[(rx*8+l)*STR + (d4 ^ (rx&7))];
#pragma unroll
      for (int k=0;k<8;++k)
#pragma unroll
        for (int l=0;l<8;++l)
          acc[k][l] += a_[k].x*b_[l].x + a_[k].y*b_[l].y + a_[k].z*b_[l].z + a_[k].w*b_[l].w;
    }
  }
  const float* sqb = sq + (size_t)b*NP;
  float sn[8], sm[8];
#pragma unroll
  for (int k=0;k<8;++k){ sn[k] = sqb[n0+ry*8+k]; sm[k] = sqb[m0+rx*8+k]; }
  float* dbase = dist + ((size_t)bz*NP + n0 + ry*8)*NP + m0 + rx*8;
#pragma unroll
  for (int k=0;k<8;++k){
    float r[8];
#pragma unroll
    for (int l=0;l<8;++l) r[l] = (sn[k]+sm[l]) - 2.f*acc[k][l];
    st4(dbase + (size_t)k*NP,     make_float4(r[0],r[1],r[2],r[3]));
    st4(dbase + (size_t)k*NP + 4, make_float4(r[4],r[5],r[6],r[7]));
  }
}

// ---------------- top-k selection (wave per row) ----------------
__global__ __launch_bounds__(256) void k_topk(const float* __restrict__ dist,
    int* __restrict__ idx, int b0){
  int wave = threadIdx.x>>6, lane = threadIdx.x&63;
  int rowg = blockIdx.x*4 + wave;          // = bz*NP + n
  int bz = rowg >> 10, n = rowg & 1023;
  const float* dr = dist + (size_t)rowg * NP;
  float dv[16];
#pragma unroll
  for (int t=0;t<16;++t) dv[t] = dr[lane + 64*t];
  int* out = idx + ((size_t)(b0+bz)*NP + n)*NK;
  for (int kk=0; kk<NK; ++kk){
    float bvv = dv[0]; int bm = lane;
#pragma unroll
    for (int t=1;t<16;++t){
      int m = lane + 64*t;
      if (dv[t] < bvv){ bvv = dv[t]; bm = m; }   // ascending m, strict < => lowest idx on tie
    }
#pragma unroll
    for (int off=32; off; off>>=1){
      float ov = __shfl_xor(bvv, off, 64);
      int om = __shfl_xor(bm, off, 64);
      if (ov < bvv || (ov == bvv && om < bm)){ bvv = ov; bm = om; }
    }
    if (lane == 0) out[kk] = bm;
    int tsel = bm>>6, lsel = bm&63;
#pragma unroll
    for (int t=0;t<16;++t)
      if (t == tsel && lane == lsel) dv[t] = __builtin_inff();   // static indexing
  }
}

// ---------------- edge conv layer 1 (din=2, dout=64) ----------------
__global__ __launch_bounds__(256) void k_edge1(const float* __restrict__ x,
    const int* __restrict__ idx, const float* __restrict__ W,
    const float* __restrict__ bias, float* __restrict__ hout,
    float* __restrict__ stats){
  __shared__ int idx_s[4][NK];
  __shared__ float red[4][64];
  int p = threadIdx.x>>6, o = threadIdx.x&63;
  int p0 = blockIdx.x*4;
  int b = p0 >> 10;
  int pl0 = p0 & 1023;
  const float* xb = x + ((size_t)b<<10)*2;
  if (threadIdx.x < 4*NK) idx_s[threadIdx.x/NK][threadIdx.x%NK] = idx[(size_t)p0*NK + threadIdx.x];
  __syncthreads();
  float w0=W[o], w1=W[64+o], w2=W[128+o], w3=W[192+o];
  float2 xi = ld2(xb + (size_t)(pl0+p)*2);
  float common = xi.x*w0 + xi.y*w1 + bias[o];
  float mv = -__builtin_inff();
  for (int j=0;j<NK;++j){
    float2 xj = ld2(xb + (size_t)idx_s[p][j]*2);
    mv = fmaxf(mv, (xj.x-xi.x)*w2 + (xj.y-xi.y)*w3);
  }
  float v = fmaxf(common + mv, 0.f);
  hout[(size_t)(p0+p)*64 + o] = v;
  red[p][o] = v;
  float ss = v*v;
#pragma unroll
  for (int off=32; off; off>>=1) ss += __shfl_xor(ss, off, 64);
  if ((threadIdx.x&63)==0) atomicAdd(stats+256, ss);
  __syncthreads();
  if (threadIdx.x < 64){
    float s = red[0][o]+red[1][o]+red[2][o]+red[3][o];
    atomicAdd(stats + o, s);
  }
}

// ---------------- edge conv generic (layers 2,3) ----------------
// msg = xi@Wtop + (xj-xi)@Wbot + b ; out = relu(max_j msg). 11 passes: j=0..9 delta, pass 10 = xi/common.
template<int DIN, int DOUT, int BP, int TPP>
__global__ __launch_bounds__(256,2) void k_edge(const float* __restrict__ x,
    const int* __restrict__ idx, const float* __restrict__ W,
    const float* __restrict__ bias, float* __restrict__ hout,
    float* __restrict__ stats){
  constexpr int TO = 8;
  constexpr int OG = DOUT/TO;
  constexpr int PG = 256/OG;
  static_assert(PG*TPP == BP, "geometry");
  constexpr int C4 = DIN/4;
  constexpr int STR = C4+1;
  __shared__ float4 ds_[BP*STR];
  __shared__ int idx_s[BP][NK];
  int og = threadIdx.x % OG;
  int pg = threadIdx.x / OG;
  int o0 = og*TO;
  int p0 = blockIdx.x*BP;
  int b = p0>>10;
  int pl0 = p0 & 1023;
  const float* xb = x + ((size_t)b<<10)*DIN;
  for (int t=threadIdx.x; t<BP*NK; t+=256)
    idx_s[t/NK][t%NK] = idx[(size_t)p0*NK + t];
  float maxv[TPP][TO], acc[TPP][TO];
#pragma unroll
  for (int k=0;k<TPP;++k)
#pragma unroll
    for (int i=0;i<TO;++i) maxv[k][i] = -__builtin_inff();
  float4 bA = ld4(bias+o0), bB = ld4(bias+o0+4);

  for (int jj=0; jj<=NK; ++jj){
    bool isC = (jj==NK);
    __syncthreads();
    for (int u=threadIdx.x; u<BP*C4; u+=256){
      int pp = u / C4, c = u % C4;
      float4 xi = ld4(xb + (size_t)(pl0+pp)*DIN + 4*c);
      if (!isC){
        float4 xj = ld4(xb + (size_t)idx_s[pp][jj]*DIN + 4*c);
        xi = make_float4(xj.x-xi.x, xj.y-xi.y, xj.z-xi.z, xj.w-xi.w);
      }
      ds_[pp*STR + c] = xi;
    }
    __syncthreads();
#pragma unroll
    for (int k=0;k<TPP;++k){
      acc[k][0]=isC?bA.x:0.f; acc[k][1]=isC?bA.y:0.f; acc[k][2]=isC?bA.z:0.f; acc[k][3]=isC?bA.w:0.f;
      acc[k][4]=isC?bB.x:0.f; acc[k][5]=isC?bB.y:0.f; acc[k][6]=isC?bB.z:0.f; acc[k][7]=isC?bB.w:0.f;
    }
    const float* Wb = W + (isC ? (size_t)0 : (size_t)DIN*DOUT);
    for (int d4=0; d4<C4; ++d4){
      float4 dl[TPP];
#pragma unroll
      for (int k=0;k<TPP;++k) dl[k] = ds_[(pg*TPP+k)*STR + d4];
#pragma unroll
      for (int dd=0; dd<4; ++dd){
        const float* wr = Wb + (size_t)(4*d4+dd)*DOUT + o0;
        float4 wA = ld4(wr), wB = ld4(wr+4);
#pragma unroll
        for (int k=0;k<TPP;++k){
          float dv = dd==0?dl[k].x : dd==1?dl[k].y : dd==2?dl[k].z : dl[k].w;
          acc[k][0] += dv*wA.x; acc[k][1] += dv*wA.y; acc[k][2] += dv*wA.z; acc[k][3] += dv*wA.w;
          acc[k][4] += dv*wB.x; acc[k][5] += dv*wB.y; acc[k][6] += dv*wB.z; acc[k][7] += dv*wB.w;
        }
      }
    }
    if (!isC){
#pragma unroll
      for (int k=0;k<TPP;++k)
#pragma unroll
        for (int i=0;i<TO;++i) maxv[k][i] = fmaxf(maxv[k][i], acc[k][i]);
    }
  }
  // acc holds common; fold max + relu
#pragma unroll
  for (int k=0;k<TPP;++k)
#pragma unroll
    for (int i=0;i<TO;++i) acc[k][i] = fmaxf(acc[k][i] + maxv[k][i], 0.f);
#pragma unroll
  for (int k=0;k<TPP;++k){
    float* hp = hout + (size_t)(p0 + pg*TPP + k)*DOUT + o0;
    st4(hp,   make_float4(acc[k][0],acc[k][1],acc[k][2],acc[k][3]));
    st4(hp+4, make_float4(acc[k][4],acc[k][5],acc[k][6],acc[k][7]));
  }
  // stats: total sum-of-squares + per-feature sums (for PairNorm)
  float ss = 0.f;
#pragma unroll
  for (int k=0;k<TPP;++k)
#pragma unroll
    for (int i=0;i<TO;++i) ss += acc[k][i]*acc[k][i];
#pragma unroll
  for (int off=32; off; off>>=1) ss += __shfl_xor(ss, off, 64);
  if ((threadIdx.x&63)==0) atomicAdd(stats+256, ss);
  __syncthreads();                      // ds_ reuse as reduction scratch
  float* red = reinterpret_cast<float*>(ds_);
#pragma unroll
  for (int i=0;i<TO;++i){
    float s = 0.f;
#pragma unroll
    for (int k=0;k<TPP;++k) s += acc[k][i];
    red[pg*DOUT + o0 + i] = s;
  }
  __syncthreads();
  for (int o=threadIdx.x; o<DOUT; o+=256){
    float s = 0.f;
    for (int g=0; g<PG; ++g) s += red[g*DOUT + o];
    atomicAdd(stats + o, s);
  }
}

// ---------------- finalize PairNorm stats ----------------
__global__ __launch_bounds__(256) void k_finalize(float* stats, int dout){
  __shared__ float part[4];
  int o = threadIdx.x;
  float m = (o < dout) ? stats[o] * (1.f/BN) : 0.f;
  stats[320+o] = m;                    // mu
  float p = m*m;
#pragma unroll
  for (int off=32; off; off>>=1) p += __shfl_xor(p, off, 64);
  if ((o&63)==0) part[o>>6] = p;
  __syncthreads();
  if (o==0){
    float s = part[0]+part[1]+part[2]+part[3];
    float msn = stats[256]*(1.f/BN) - s;
    stats[576] = 1.f / sqrtf(1e-5f + msn);
  }
}

// ---------------- normalize in place + next-layer sq ----------------
template<int DOUT>
__global__ __launch_bounds__(256) void k_norm(float* __restrict__ h,
    const float* __restrict__ stats, float* __restrict__ sq){
  __shared__ float part[4];
  int row = blockIdx.x, o = threadIdx.x;
  float inv = stats[576];
  float v = (h[(size_t)row*DOUT + o] - stats[320+o]) * inv;
  h[(size_t)row*DOUT + o] = v;
  float s = v*v;
#pragma unroll
  for (int off=32; off; off>>=1) s += __shfl_xor(s, off, 64);
  if constexpr (DOUT==64){
    if (o==0) sq[row] = s;
  } else {
    if ((o&63)==0) part[o>>6] = s;
    __syncthreads();
    if (o==0){ float t=0.f; for (int w2=0; w2<DOUT/64; ++w2) t += part[w2]; sq[row] = t; }
  }
}

// ---------------- global max pool (partial) ----------------
__global__ __launch_bounds__(256) void k_pool1(const float* __restrict__ h, float* __restrict__ gpart){
  int b = blockIdx.x, c = blockIdx.y, o = threadIdx.x;
  const float* hp = h + ((size_t)b*NP + c*128)*256 + o;
  float m = -__builtin_inff();
  for (int n=0;n<128;++n) m = fmaxf(m, hp[(size_t)n*256]);
  gpart[((size_t)c*NB + b)*256 + o] = m;
}

// ---------------- pool finish + MLP head ----------------
__global__ __launch_bounds__(256) void k_head(const float* __restrict__ gpart,
    const float* __restrict__ Wl1, const float* __restrict__ bl1,
    const float* __restrict__ Wl2, const float* __restrict__ bl2,
    float* __restrict__ out){
  __shared__ float g_s[256];
  __shared__ float h_s[64];
  int b = blockIdx.x, t = threadIdx.x;
  float m = -__builtin_inff();
  for (int c=0;c<8;++c) m = fmaxf(m, gpart[((size_t)c*NB + b)*256 + t]);
  g_s[t] = m;
  __syncthreads();
  if (t < 64){
    float a = bl1[t];
    for (int k=0;k<256;++k) a += g_s[k]*Wl1[(size_t)k*64 + t];
    h_s[t] = fmaxf(a, 0.f);
  }
  __syncthreads();
  if (t < 2){
    float a = bl2[t];
    for (int i=0;i<64;++i) a += h_s[i]*Wl2[(size_t)i*2 + t];
    out[(size_t)b*2 + t] = a;
  }
}

extern "C" void kernel_launch(void* const* d_in, const int* in_sizes, int n_in,
                              void* d_out, int out_size, void* d_ws, size_t ws_size,
                              hipStream_t stream){
  (void)in_sizes; (void)n_in; (void)out_size; (void)ws_size;
  const float* pos = (const float*)d_in[0];
  const float* W1  = (const float*)d_in[1];
  const float* b1  = (const float*)d_in[2];
  const float* W2  = (const float*)d_in[3];
  const float* b2  = (const float*)d_in[4];
  const float* W3  = (const float*)d_in[5];
  const float* b3  = (const float*)d_in[6];
  const float* Wl1 = (const float*)d_in[7];
  const float* bl1 = (const float*)d_in[8];
  const float* Wl2 = (const float*)d_in[9];
  const float* bl2 = (const float*)d_in[10];
  float* outp = (float*)d_out;

  char* w = (char*)d_ws;
  size_t off = 0;
  auto take = [&](size_t bytes)->char*{ char* p = w + off; off += (bytes + 255) & ~(size_t)255; return p; };
  float* sq    = (float*)take((size_t)BN*4);
  int*   idx   = (int*)  take((size_t)BN*NK*4);
  float* x1    = (float*)take((size_t)BN*64*4);
  float* x2    = (float*)take((size_t)BN*128*4);
  float* x3    = (float*)take((size_t)BN*256*4);
  float* stats = (float*)take(4096);
  float* gpart = (float*)take((size_t)8*NB*256*4);
  float* dist  = (float*)take((size_t)NBCH*NP*NP*4);   // total ~94 MB

  dim3 gdist(NP/128, NP/128, NBCH);

  // ---- layer 1 ----
  k_sq_pos<<<BN/256, 256, 0, stream>>>(pos, sq);
  for (int c=0;c<NB/NBCH;++c){
    k_dist2<<<gdist, 256, 0, stream>>>(pos, sq, dist, c*NBCH);
    k_topk<<<NBCH*NP/4, 256, 0, stream>>>(dist, idx, c*NBCH);
  }
  hipMemsetAsync(stats, 0, 4096, stream);
  k_edge1<<<BN/4, 256, 0, stream>>>(pos, idx, W1, b1, x1, stats);
  k_finalize<<<1, 256, 0, stream>>>(stats, 64);
  k_norm<64><<<BN, 64, 0, stream>>>(x1, stats, sq);

  // ---- layer 2 ----
  for (int c=0;c<NB/NBCH;++c){
    k_dist<64><<<gdist, 256, 0, stream>>>(x1, sq, dist, c*NBCH);
    k_topk<<<NBCH*NP/4, 256, 0, stream>>>(dist, idx, c*NBCH);
  }
  hipMemsetAsync(stats, 0, 4096, stream);
  k_edge<64,128,64,4><<<BN/64, 256, 0, stream>>>(x1, idx, W2, b2, x2, stats);
  k_finalize<<<1, 256, 0, stream>>>(stats, 128);
  k_norm<128><<<BN, 128, 0, stream>>>(x2, stats, sq);

  // ---- layer 3 ----
  for (int c=0;c<NB/NBCH;++c){
    k_dist<128><<<gdist, 256, 0, stream>>>(x2, sq, dist, c*NBCH);
    k_topk<<<NBCH*NP/4, 256, 0, stream>>>(dist, idx, c*NBCH);
  }
  hipMemsetAsync(stats, 0, 4096, stream);
  k_edge<128,256,64,8><<<BN/64, 256, 0, stream>>>(x2, idx, W3, b3, x3, stats);
  k_finalize<<<1, 256, 0, stream>>>(stats, 256);
  k_norm<256><<<BN, 256, 0, stream>>>(x3, stats, sq);

  // ---- pool + head ----
  k_pool1<<<dim3(NB, 8), 256, 0, stream>>>(x3, gpart);
  k_head<<<NB, 256, 0, stream>>>(gpart, Wl1, bl1, Wl2, bl2, outp);
}

// Round 2
// 2155.406 us; speedup vs baseline: 2.2337x; 2.2337x over previous
//
#include <hip/hip_runtime.h>
#include <math.h>

constexpr int NB = 32;      // batches
constexpr int NP = 1024;    // points per batch
constexpr int NK = 10;      // k nearest (includes self)
constexpr int BN = NB * NP;
constexpr int NBCH = 8;     // batches per dist chunk

__device__ __forceinline__ float4 ld4(const float* p){ return *reinterpret_cast<const float4*>(p); }
__device__ __forceinline__ float2 ld2(const float* p){ return *reinterpret_cast<const float2*>(p); }
__device__ __forceinline__ void st4(float* p, float4 v){ *reinterpret_cast<float4*>(p) = v; }

// ---------------- sq norms of pos ----------------
__global__ __launch_bounds__(256) void k_sq_pos(const float* __restrict__ x, float* __restrict__ sq){
  int i = blockIdx.x*256 + threadIdx.x;
  float2 v = ld2(x + (size_t)2*i);
  sq[i] = v.x*v.x + v.y*v.y;
}

// ---------------- dist matrix, DIN=2 (layer 1) ----------------
__global__ __launch_bounds__(256) void k_dist2(const float* __restrict__ x,
    const float* __restrict__ sq, float* __restrict__ dist, int b0){
  int bz = blockIdx.z;
  int b = b0 + bz;
  int n0 = blockIdx.x*128, m0 = blockIdx.y*128;
  int ry = threadIdx.x>>4, rx = threadIdx.x&15;
  const float* xb = x + (size_t)b*NP*2;
  const float* sqb = sq + (size_t)b*NP;
  float2 av[8], bv[8]; float sn[8], sm[8];
#pragma unroll
  for (int k=0;k<8;++k){
    av[k] = ld2(xb + (size_t)(n0+ry*8+k)*2);
    bv[k] = ld2(xb + (size_t)(m0+rx*8+k)*2);
    sn[k] = sqb[n0+ry*8+k];
    sm[k] = sqb[m0+rx*8+k];
  }
  float* dbase = dist + ((size_t)bz*NP + n0 + ry*8)*NP + m0 + rx*8;
#pragma unroll
  for (int k=0;k<8;++k){
    float r[8];
#pragma unroll
    for (int l=0;l<8;++l){
      float dot = av[k].x*bv[l].x + av[k].y*bv[l].y;
      r[l] = (sn[k] + sm[l]) - 2.f*dot;
    }
    st4(dbase + (size_t)k*NP,     make_float4(r[0],r[1],r[2],r[3]));
    st4(dbase + (size_t)k*NP + 4, make_float4(r[4],r[5],r[6],r[7]));
  }
}

// ---------------- dist matrix, DIN in {64,128} ----------------
// NOTE: no min-occupancy cap — 8x8 fp32 tile needs ~180 VGPR; capping at 128
// caused catastrophic scratch spill (round 1: 1.8 GB HBM traffic/dispatch).
template<int DIN>
__global__ __launch_bounds__(256) void k_dist(const float* __restrict__ x,
    const float* __restrict__ sq, float* __restrict__ dist, int b0){
  constexpr int CH = 32, C4 = 8, STR = 9;   // 32-dim chunks, 8 f4 + 1 pad per row
  __shared__ float4 as_[128*STR];
  __shared__ float4 bs_[128*STR];
  int bz = blockIdx.z;
  int b = b0 + bz;
  int n0 = blockIdx.x*128, m0 = blockIdx.y*128;
  int ry = threadIdx.x>>4, rx = threadIdx.x&15;
  const float* xb = x + (size_t)b*NP*DIN;
  float acc[8][8];
#pragma unroll
  for (int k=0;k<8;++k)
#pragma unroll
    for (int l=0;l<8;++l) acc[k][l] = 0.f;
  for (int ch=0; ch<DIN/CH; ++ch){
    __syncthreads();
    for (int u=threadIdx.x; u<128*C4; u+=256){
      int r = u>>3, c = u&7;
      int sw = c ^ ((r>>3)&7);              // XOR swizzle: conflict-free b128 reads
      as_[r*STR + sw] = ld4(xb + (size_t)(n0+r)*DIN + ch*CH + 4*c);
      bs_[r*STR + sw] = ld4(xb + (size_t)(m0+r)*DIN + ch*CH + 4*c);
    }
    __syncthreads();
#pragma unroll
    for (int d4=0; d4<C4; ++d4){
      float4 a_[8], b_[8];
#pragma unroll
      for (int k=0;k<8;++k) a_[k] = as_[(ry*8+k)*STR + (d4 ^ (ry&7))];
#pragma unroll
      for (int l=0;l<8;++l) b_[l] = bs_[(rx*8+l)*STR + (d4 ^ (rx&7))];
#pragma unroll
      for (int k=0;k<8;++k)
#pragma unroll
        for (int l=0;l<8;++l)
          acc[k][l] += a_[k].x*b_[l].x + a_[k].y*b_[l].y + a_[k].z*b_[l].z + a_[k].w*b_[l].w;
    }
  }
  const float* sqb = sq + (size_t)b*NP;
  float sn[8], sm[8];
#pragma unroll
  for (int k=0;k<8;++k){ sn[k] = sqb[n0+ry*8+k]; sm[k] = sqb[m0+rx*8+k]; }
  float* dbase = dist + ((size_t)bz*NP + n0 + ry*8)*NP + m0 + rx*8;
#pragma unroll
  for (int k=0;k<8;++k){
    float r[8];
#pragma unroll
    for (int l=0;l<8;++l) r[l] = (sn[k]+sm[l]) - 2.f*acc[k][l];
    st4(dbase + (size_t)k*NP,     make_float4(r[0],r[1],r[2],r[3]));
    st4(dbase + (size_t)k*NP + 4, make_float4(r[4],r[5],r[6],r[7]));
  }
}

// ---------------- top-k selection (wave per row) ----------------
__global__ __launch_bounds__(256) void k_topk(const float* __restrict__ dist,
    int* __restrict__ idx, int b0){
  int wave = threadIdx.x>>6, lane = threadIdx.x&63;
  int rowg = blockIdx.x*4 + wave;          // = bz*NP + n
  int bz = rowg >> 10, n = rowg & 1023;
  const float* dr = dist + (size_t)rowg * NP;
  float dv[16];
#pragma unroll
  for (int t=0;t<16;++t) dv[t] = dr[lane + 64*t];
  int* out = idx + ((size_t)(b0+bz)*NP + n)*NK;
  for (int kk=0; kk<NK; ++kk){
    float bvv = dv[0]; int bm = lane;
#pragma unroll
    for (int t=1;t<16;++t){
      int m = lane + 64*t;
      if (dv[t] < bvv){ bvv = dv[t]; bm = m; }   // ascending m, strict < => lowest idx on tie
    }
#pragma unroll
    for (int off=32; off; off>>=1){
      float ov = __shfl_xor(bvv, off, 64);
      int om = __shfl_xor(bm, off, 64);
      if (ov < bvv || (ov == bvv && om < bm)){ bvv = ov; bm = om; }
    }
    if (lane == 0) out[kk] = bm;
    int tsel = bm>>6, lsel = bm&63;
#pragma unroll
    for (int t=0;t<16;++t)
      if (t == tsel && lane == lsel) dv[t] = __builtin_inff();   // static indexing
  }
}

// ---------------- edge conv layer 1 (din=2, dout=64) ----------------
__global__ __launch_bounds__(256) void k_edge1(const float* __restrict__ x,
    const int* __restrict__ idx, const float* __restrict__ W,
    const float* __restrict__ bias, float* __restrict__ hout,
    float* __restrict__ stats){
  __shared__ int idx_s[4][NK];
  __shared__ float red[4][64];
  int p = threadIdx.x>>6, o = threadIdx.x&63;
  int p0 = blockIdx.x*4;
  int b = p0 >> 10;
  int pl0 = p0 & 1023;
  const float* xb = x + ((size_t)b<<10)*2;
  if (threadIdx.x < 4*NK) idx_s[threadIdx.x/NK][threadIdx.x%NK] = idx[(size_t)p0*NK + threadIdx.x];
  __syncthreads();
  float w0=W[o], w1=W[64+o], w2=W[128+o], w3=W[192+o];
  float2 xi = ld2(xb + (size_t)(pl0+p)*2);
  float common = xi.x*w0 + xi.y*w1 + bias[o];
  float mv = -__builtin_inff();
  for (int j=0;j<NK;++j){
    float2 xj = ld2(xb + (size_t)idx_s[p][j]*2);
    mv = fmaxf(mv, (xj.x-xi.x)*w2 + (xj.y-xi.y)*w3);
  }
  float v = fmaxf(common + mv, 0.f);
  hout[(size_t)(p0+p)*64 + o] = v;
  red[p][o] = v;
  float ss = v*v;
#pragma unroll
  for (int off=32; off; off>>=1) ss += __shfl_xor(ss, off, 64);
  if ((threadIdx.x&63)==0) atomicAdd(stats+256, ss);
  __syncthreads();
  if (threadIdx.x < 64){
    float s = red[0][o]+red[1][o]+red[2][o]+red[3][o];
    atomicAdd(stats + o, s);
  }
}

// ---------------- edge conv generic (layers 2,3) ----------------
// msg = xi@Wtop + (xj-xi)@Wbot + b ; out = relu(max_j msg). 11 passes: j=0..9 delta, pass 10 = xi/common.
template<int DIN, int DOUT, int BP, int TPP>
__global__ __launch_bounds__(256) void k_edge(const float* __restrict__ x,
    const int* __restrict__ idx, const float* __restrict__ W,
    const float* __restrict__ bias, float* __restrict__ hout,
    float* __restrict__ stats){
  constexpr int TO = 8;
  constexpr int OG = DOUT/TO;
  constexpr int PG = 256/OG;
  static_assert(PG*TPP == BP, "geometry");
  constexpr int C4 = DIN/4;
  constexpr int STR = C4+1;
  __shared__ float4 ds_[BP*STR];
  __shared__ int idx_s[BP][NK];
  int og = threadIdx.x % OG;
  int pg = threadIdx.x / OG;
  int o0 = og*TO;
  int p0 = blockIdx.x*BP;
  int b = p0>>10;
  int pl0 = p0 & 1023;
  const float* xb = x + ((size_t)b<<10)*DIN;
  for (int t=threadIdx.x; t<BP*NK; t+=256)
    idx_s[t/NK][t%NK] = idx[(size_t)p0*NK + t];
  float maxv[TPP][TO], acc[TPP][TO];
#pragma unroll
  for (int k=0;k<TPP;++k)
#pragma unroll
    for (int i=0;i<TO;++i) maxv[k][i] = -__builtin_inff();
  float4 bA = ld4(bias+o0), bB = ld4(bias+o0+4);

  for (int jj=0; jj<=NK; ++jj){
    bool isC = (jj==NK);
    __syncthreads();
    for (int u=threadIdx.x; u<BP*C4; u+=256){
      int pp = u / C4, c = u % C4;
      float4 xi = ld4(xb + (size_t)(pl0+pp)*DIN + 4*c);
      if (!isC){
        float4 xj = ld4(xb + (size_t)idx_s[pp][jj]*DIN + 4*c);
        xi = make_float4(xj.x-xi.x, xj.y-xi.y, xj.z-xi.z, xj.w-xi.w);
      }
      ds_[pp*STR + c] = xi;
    }
    __syncthreads();
#pragma unroll
    for (int k=0;k<TPP;++k){
      acc[k][0]=isC?bA.x:0.f; acc[k][1]=isC?bA.y:0.f; acc[k][2]=isC?bA.z:0.f; acc[k][3]=isC?bA.w:0.f;
      acc[k][4]=isC?bB.x:0.f; acc[k][5]=isC?bB.y:0.f; acc[k][6]=isC?bB.z:0.f; acc[k][7]=isC?bB.w:0.f;
    }
    const float* Wb = W + (isC ? (size_t)0 : (size_t)DIN*DOUT);
    for (int d4=0; d4<C4; ++d4){
      float4 dl[TPP];
#pragma unroll
      for (int k=0;k<TPP;++k) dl[k] = ds_[(pg*TPP+k)*STR + d4];
#pragma unroll
      for (int dd=0; dd<4; ++dd){
        const float* wr = Wb + (size_t)(4*d4+dd)*DOUT + o0;
        float4 wA = ld4(wr), wB = ld4(wr+4);
#pragma unroll
        for (int k=0;k<TPP;++k){
          float dv = dd==0?dl[k].x : dd==1?dl[k].y : dd==2?dl[k].z : dl[k].w;
          acc[k][0] += dv*wA.x; acc[k][1] += dv*wA.y; acc[k][2] += dv*wA.z; acc[k][3] += dv*wA.w;
          acc[k][4] += dv*wB.x; acc[k][5] += dv*wB.y; acc[k][6] += dv*wB.z; acc[k][7] += dv*wB.w;
        }
      }
    }
    if (!isC){
#pragma unroll
      for (int k=0;k<TPP;++k)
#pragma unroll
        for (int i=0;i<TO;++i) maxv[k][i] = fmaxf(maxv[k][i], acc[k][i]);
    }
  }
  // acc holds common; fold max + relu
#pragma unroll
  for (int k=0;k<TPP;++k)
#pragma unroll
    for (int i=0;i<TO;++i) acc[k][i] = fmaxf(acc[k][i] + maxv[k][i], 0.f);
#pragma unroll
  for (int k=0;k<TPP;++k){
    float* hp = hout + (size_t)(p0 + pg*TPP + k)*DOUT + o0;
    st4(hp,   make_float4(acc[k][0],acc[k][1],acc[k][2],acc[k][3]));
    st4(hp+4, make_float4(acc[k][4],acc[k][5],acc[k][6],acc[k][7]));
  }
  // stats: total sum-of-squares + per-feature sums (for PairNorm)
  float ss = 0.f;
#pragma unroll
  for (int k=0;k<TPP;++k)
#pragma unroll
    for (int i=0;i<TO;++i) ss += acc[k][i]*acc[k][i];
#pragma unroll
  for (int off=32; off; off>>=1) ss += __shfl_xor(ss, off, 64);
  if ((threadIdx.x&63)==0) atomicAdd(stats+256, ss);
  __syncthreads();                      // ds_ reuse as reduction scratch
  float* red = reinterpret_cast<float*>(ds_);
#pragma unroll
  for (int i=0;i<TO;++i){
    float s = 0.f;
#pragma unroll
    for (int k=0;k<TPP;++k) s += acc[k][i];
    red[pg*DOUT + o0 + i] = s;
  }
  __syncthreads();
  for (int o=threadIdx.x; o<DOUT; o+=256){
    float s = 0.f;
    for (int g=0; g<PG; ++g) s += red[g*DOUT + o];
    atomicAdd(stats + o, s);
  }
}

// ---------------- finalize PairNorm stats ----------------
__global__ __launch_bounds__(256) void k_finalize(float* stats, int dout){
  __shared__ float part[4];
  int o = threadIdx.x;
  float m = (o < dout) ? stats[o] * (1.f/BN) : 0.f;
  stats[320+o] = m;                    // mu
  float p = m*m;
#pragma unroll
  for (int off=32; off; off>>=1) p += __shfl_xor(p, off, 64);
  if ((o&63)==0) part[o>>6] = p;
  __syncthreads();
  if (o==0){
    float s = part[0]+part[1]+part[2]+part[3];
    float msn = stats[256]*(1.f/BN) - s;
    stats[576] = 1.f / sqrtf(1e-5f + msn);
  }
}

// ---------------- normalize in place + next-layer sq ----------------
template<int DOUT>
__global__ __launch_bounds__(256) void k_norm(float* __restrict__ h,
    const float* __restrict__ stats, float* __restrict__ sq){
  __shared__ float part[4];
  int row = blockIdx.x, o = threadIdx.x;
  float inv = stats[576];
  float v = (h[(size_t)row*DOUT + o] - stats[320+o]) * inv;
  h[(size_t)row*DOUT + o] = v;
  float s = v*v;
#pragma unroll
  for (int off=32; off; off>>=1) s += __shfl_xor(s, off, 64);
  if constexpr (DOUT==64){
    if (o==0) sq[row] = s;
  } else {
    if ((o&63)==0) part[o>>6] = s;
    __syncthreads();
    if (o==0){ float t=0.f; for (int w2=0; w2<DOUT/64; ++w2) t += part[w2]; sq[row] = t; }
  }
}

// ---------------- global max pool (partial) ----------------
__global__ __launch_bounds__(256) void k_pool1(const float* __restrict__ h, float* __restrict__ gpart){
  int b = blockIdx.x, c = blockIdx.y, o = threadIdx.x;
  const float* hp = h + ((size_t)b*NP + c*128)*256 + o;
  float m = -__builtin_inff();
  for (int n=0;n<128;++n) m = fmaxf(m, hp[(size_t)n*256]);
  gpart[((size_t)c*NB + b)*256 + o] = m;
}

// ---------------- pool finish + MLP head ----------------
__global__ __launch_bounds__(256) void k_head(const float* __restrict__ gpart,
    const float* __restrict__ Wl1, const float* __restrict__ bl1,
    const float* __restrict__ Wl2, const float* __restrict__ bl2,
    float* __restrict__ out){
  __shared__ float g_s[256];
  __shared__ float h_s[64];
  int b = blockIdx.x, t = threadIdx.x;
  float m = -__builtin_inff();
  for (int c=0;c<8;++c) m = fmaxf(m, gpart[((size_t)c*NB + b)*256 + t]);
  g_s[t] = m;
  __syncthreads();
  if (t < 64){
    float a = bl1[t];
    for (int k=0;k<256;++k) a += g_s[k]*Wl1[(size_t)k*64 + t];
    h_s[t] = fmaxf(a, 0.f);
  }
  __syncthreads();
  if (t < 2){
    float a = bl2[t];
    for (int i=0;i<64;++i) a += h_s[i]*Wl2[(size_t)i*2 + t];
    out[(size_t)b*2 + t] = a;
  }
}

extern "C" void kernel_launch(void* const* d_in, const int* in_sizes, int n_in,
                              void* d_out, int out_size, void* d_ws, size_t ws_size,
                              hipStream_t stream){
  (void)in_sizes; (void)n_in; (void)out_size; (void)ws_size;
  const float* pos = (const float*)d_in[0];
  const float* W1  = (const float*)d_in[1];
  const float* b1  = (const float*)d_in[2];
  const float* W2  = (const float*)d_in[3];
  const float* b2  = (const float*)d_in[4];
  const float* W3  = (const float*)d_in[5];
  const float* b3  = (const float*)d_in[6];
  const float* Wl1 = (const float*)d_in[7];
  const float* bl1 = (const float*)d_in[8];
  const float* Wl2 = (const float*)d_in[9];
  const float* bl2 = (const float*)d_in[10];
  float* outp = (float*)d_out;

  char* w = (char*)d_ws;
  size_t off = 0;
  auto take = [&](size_t bytes)->char*{ char* p = w + off; off += (bytes + 255) & ~(size_t)255; return p; };
  float* sq    = (float*)take((size_t)BN*4);
  int*   idx   = (int*)  take((size_t)BN*NK*4);
  float* x1    = (float*)take((size_t)BN*64*4);
  float* x2    = (float*)take((size_t)BN*128*4);
  float* x3    = (float*)take((size_t)BN*256*4);
  float* stats = (float*)take(4096);
  float* gpart = (float*)take((size_t)8*NB*256*4);
  float* dist  = (float*)take((size_t)NBCH*NP*NP*4);   // total ~94 MB

  dim3 gdist(NP/128, NP/128, NBCH);

  // ---- layer 1 ----
  k_sq_pos<<<BN/256, 256, 0, stream>>>(pos, sq);
  for (int c=0;c<NB/NBCH;++c){
    k_dist2<<<gdist, 256, 0, stream>>>(pos, sq, dist, c*NBCH);
    k_topk<<<NBCH*NP/4, 256, 0, stream>>>(dist, idx, c*NBCH);
  }
  hipMemsetAsync(stats, 0, 4096, stream);
  k_edge1<<<BN/4, 256, 0, stream>>>(pos, idx, W1, b1, x1, stats);
  k_finalize<<<1, 256, 0, stream>>>(stats, 64);
  k_norm<64><<<BN, 64, 0, stream>>>(x1, stats, sq);

  // ---- layer 2 ----
  for (int c=0;c<NB/NBCH;++c){
    k_dist<64><<<gdist, 256, 0, stream>>>(x1, sq, dist, c*NBCH);
    k_topk<<<NBCH*NP/4, 256, 0, stream>>>(dist, idx, c*NBCH);
  }
  hipMemsetAsync(stats, 0, 4096, stream);
  k_edge<64,128,64,4><<<BN/64, 256, 0, stream>>>(x1, idx, W2, b2, x2, stats);
  k_finalize<<<1, 256, 0, stream>>>(stats, 128);
  k_norm<128><<<BN, 128, 0, stream>>>(x2, stats, sq);

  // ---- layer 3 ----
  for (int c=0;c<NB/NBCH;++c){
    k_dist<128><<<gdist, 256, 0, stream>>>(x2, sq, dist, c*NBCH);
    k_topk<<<NBCH*NP/4, 256, 0, stream>>>(dist, idx, c*NBCH);
  }
  hipMemsetAsync(stats, 0, 4096, stream);
  k_edge<128,256,32,4><<<BN/32, 256, 0, stream>>>(x2, idx, W3, b3, x3, stats);
  k_finalize<<<1, 256, 0, stream>>>(stats, 256);
  k_norm<256><<<BN, 256, 0, stream>>>(x3, stats, sq);

  // ---- pool + head ----
  k_pool1<<<dim3(NB, 8), 256, 0, stream>>>(x3, gpart);
  k_head<<<NB, 256, 0, stream>>>(gpart, Wl1, bl1, Wl2, bl2, outp);
}

// Round 3
// 1404.012 us; speedup vs baseline: 3.4291x; 1.5352x over previous
//
#include <hip/hip_runtime.h>
#include <math.h>

constexpr int NB = 32;      // batches
constexpr int NP = 1024;    // points per batch
constexpr int NK = 10;      // k nearest (includes self)
constexpr int BN = NB * NP;
constexpr int NBCH = 8;     // batches per dist chunk

__device__ __forceinline__ float4 ld4(const float* p){ return *reinterpret_cast<const float4*>(p); }
__device__ __forceinline__ float2 ld2(const float* p){ return *reinterpret_cast<const float2*>(p); }
__device__ __forceinline__ void st4(float* p, float4 v){ *reinterpret_cast<float4*>(p) = v; }

// ---------------- sq norms of pos ----------------
__global__ __launch_bounds__(256) void k_sq_pos(const float* __restrict__ x, float* __restrict__ sq){
  int i = blockIdx.x*256 + threadIdx.x;
  float2 v = ld2(x + (size_t)2*i);
  sq[i] = v.x*v.x + v.y*v.y;
}

// ---------------- dist matrix, DIN=2 (layer 1) ----------------
__global__ __launch_bounds__(256) void k_dist2(const float* __restrict__ x,
    const float* __restrict__ sq, float* __restrict__ dist, int b0){
  int bz = blockIdx.z;
  int b = b0 + bz;
  int n0 = blockIdx.x*128, m0 = blockIdx.y*128;
  int ry = threadIdx.x>>4, rx = threadIdx.x&15;
  const float* xb = x + (size_t)b*NP*2;
  const float* sqb = sq + (size_t)b*NP;
  float2 av[8], bv[8]; float sn[8], sm[8];
#pragma unroll
  for (int k=0;k<8;++k){
    av[k] = ld2(xb + (size_t)(n0+ry*8+k)*2);
    bv[k] = ld2(xb + (size_t)(m0+rx*8+k)*2);
    sn[k] = sqb[n0+ry*8+k];
    sm[k] = sqb[m0+rx*8+k];
  }
  float* dbase = dist + ((size_t)bz*NP + n0 + ry*8)*NP + m0 + rx*8;
#pragma unroll
  for (int k=0;k<8;++k){
    float r[8];
#pragma unroll
    for (int l=0;l<8;++l){
      float dot = av[k].x*bv[l].x + av[k].y*bv[l].y;
      r[l] = (sn[k] + sm[l]) - 2.f*dot;
    }
    st4(dbase + (size_t)k*NP,     make_float4(r[0],r[1],r[2],r[3]));
    st4(dbase + (size_t)k*NP + 4, make_float4(r[4],r[5],r[6],r[7]));
  }
}

// ---------------- dist matrix, DIN in {64,128}: full-K LDS, 1 barrier ----------------
// XOR swizzle f4pos = r*K4 + ((k4 + (r>>3)) & MASK): pad-free, conflict-free reads.
template<int DIN>
__global__ __launch_bounds__(256) void k_dist(const float* __restrict__ x,
    const float* __restrict__ sq, float* __restrict__ dist, int b0){
  constexpr int K4 = DIN/4, MASK = K4-1;
  extern __shared__ float4 smem[];
  float4* as4 = smem;            // 128*K4
  float4* bs4 = smem + 128*K4;   // 128*K4
  int bz = blockIdx.z;
  int b = b0 + bz;
  int n0 = blockIdx.x*128, m0 = blockIdx.y*128;
  int ry = threadIdx.x>>4, rx = threadIdx.x&15;
  const float* xb = x + (size_t)b*NP*DIN;
  for (int u=threadIdx.x; u<128*K4; u+=256){
    int r = u / K4, c = u % K4;
    int sw = r*K4 + ((c + (r>>3)) & MASK);
    as4[sw] = ld4(xb + (size_t)(n0+r)*DIN + 4*c);
    bs4[sw] = ld4(xb + (size_t)(m0+r)*DIN + 4*c);
  }
  __syncthreads();
  float acc[8][8];
#pragma unroll
  for (int k=0;k<8;++k)
#pragma unroll
    for (int l=0;l<8;++l) acc[k][l] = 0.f;
#pragma unroll 2
  for (int d4=0; d4<K4; ++d4){
    float4 a_[8], b_[8];
#pragma unroll
    for (int k=0;k<8;++k) a_[k] = as4[(ry*8+k)*K4 + ((d4 + ry) & MASK)];
#pragma unroll
    for (int l=0;l<8;++l) b_[l] = bs4[(rx*8+l)*K4 + ((d4 + rx) & MASK)];
#pragma unroll
    for (int k=0;k<8;++k)
#pragma unroll
      for (int l=0;l<8;++l)
        acc[k][l] += a_[k].x*b_[l].x + a_[k].y*b_[l].y + a_[k].z*b_[l].z + a_[k].w*b_[l].w;
  }
  const float* sqb = sq + (size_t)b*NP;
  float sn[8], sm[8];
#pragma unroll
  for (int k=0;k<8;++k){ sn[k] = sqb[n0+ry*8+k]; sm[k] = sqb[m0+rx*8+k]; }
  float* dbase = dist + ((size_t)bz*NP + n0 + ry*8)*NP + m0 + rx*8;
#pragma unroll
  for (int k=0;k<8;++k){
    float r[8];
#pragma unroll
    for (int l=0;l<8;++l) r[l] = (sn[k]+sm[l]) - 2.f*acc[k][l];
    st4(dbase + (size_t)k*NP,     make_float4(r[0],r[1],r[2],r[3]));
    st4(dbase + (size_t)k*NP + 4, make_float4(r[4],r[5],r[6],r[7]));
  }
}

// ---------------- GEMM: xcat = x @ [Wtop | Wbot], full-K LDS ----------------
// W rows 0..DIN-1 = Wtop (xi term), DIN..2DIN-1 = Wbot (xj-xi term).
// Output row-major [rows, 2*DOUT]: cols 0..DOUT-1 = z = x@Wtop, DOUT.. = y = x@Wbot.
template<int DIN, int DOUT>
__global__ __launch_bounds__(256) void k_gemm(const float* __restrict__ x,
    const float* __restrict__ W, float* __restrict__ xcat, int m_base){
  constexpr int K4 = DIN/4, MASK = K4-1;
  extern __shared__ float4 smem[];
  float4* as4 = smem;            // 128*K4
  float4* bs4 = smem + 128*K4;   // 128*K4
  int m0 = blockIdx.x*128;                 // local row tile
  int nc = blockIdx.y*128;                 // output col tile in [0, 2*DOUT)
  bool isBot = (nc >= DOUT);
  int bcol = isBot ? nc - DOUT : nc;
  const float* B = W + (isBot ? (size_t)DIN*DOUT : 0);
  const float* xg = x + (size_t)(m_base + m0)*DIN;
  for (int u=threadIdx.x; u<128*K4; u+=256){
    int r = u / K4, c = u % K4;
    as4[r*K4 + ((c + (r>>3)) & MASK)] = ld4(xg + (size_t)r*DIN + 4*c);
  }
  float* bsf = reinterpret_cast<float*>(bs4);
  for (int u=threadIdx.x; u<DIN*128; u+=256){
    int k = u >> 7, n = u & 127;
    bsf[(n*K4 + (((k>>2) + (n>>3)) & MASK))*4 + (k&3)] = B[(size_t)k*DOUT + bcol + n];
  }
  __syncthreads();
  int ry = threadIdx.x>>4, rx = threadIdx.x&15;
  float acc[8][8];
#pragma unroll
  for (int k=0;k<8;++k)
#pragma unroll
    for (int l=0;l<8;++l) acc[k][l] = 0.f;
#pragma unroll 2
  for (int d4=0; d4<K4; ++d4){
    float4 a_[8], b_[8];
#pragma unroll
    for (int k=0;k<8;++k) a_[k] = as4[(ry*8+k)*K4 + ((d4 + ry) & MASK)];
#pragma unroll
    for (int l=0;l<8;++l) b_[l] = bs4[(rx*8+l)*K4 + ((d4 + rx) & MASK)];
#pragma unroll
    for (int k=0;k<8;++k)
#pragma unroll
      for (int l=0;l<8;++l)
        acc[k][l] += a_[k].x*b_[l].x + a_[k].y*b_[l].y + a_[k].z*b_[l].z + a_[k].w*b_[l].w;
  }
  float* outb = xcat + (size_t)(m0 + ry*8)*(2*DOUT) + nc + rx*8;
#pragma unroll
  for (int k=0;k<8;++k){
    st4(outb + (size_t)k*(2*DOUT),     make_float4(acc[k][0],acc[k][1],acc[k][2],acc[k][3]));
    st4(outb + (size_t)k*(2*DOUT) + 4, make_float4(acc[k][4],acc[k][5],acc[k][6],acc[k][7]));
  }
}

// ---------------- gather-max epilogue: h = relu(z + b - y_self + max_j y_j) ----------------
template<int DOUT>
__global__ __launch_bounds__(256) void k_gmax(const float* __restrict__ xcat,
    const int* __restrict__ idx, const float* __restrict__ bias,
    float* __restrict__ hout, float* __restrict__ stats, int p_base){
  constexpr int TP = DOUT/4;        // threads per point
  constexpr int ROWS = 256/TP;      // points in flight
  constexpr int PPT = 32/ROWS;      // points per thread
  __shared__ int idx_s[32*NK];
  __shared__ float red[1024];       // ROWS*DOUT == 1024 floats
  __shared__ float ssp[4];
  int c4 = threadIdx.x % TP, pr = threadIdx.x / TP;
  int c = 4*c4;
  int p0 = blockIdx.x*32 + p_base;          // global first point of block
  for (int t=threadIdx.x; t<32*NK; t+=256) idx_s[t] = idx[(size_t)p0*NK + t];
  __syncthreads();
  float4 b4 = ld4(bias + c);
  float4 fsum = make_float4(0.f,0.f,0.f,0.f);
  float ss = 0.f;
  int pbl = (((p0 - p_base) >> 10) << 10);  // local batch base row
#pragma unroll
  for (int t=0; t<PPT; ++t){
    int pl = pr + t*ROWS;
    int lrow = (p0 - p_base) + pl;
    const float* row = xcat + (size_t)lrow*(2*DOUT);
    float4 z = ld4(row + c), ys = ld4(row + DOUT + c);
    float4 mv = make_float4(-__builtin_inff(),-__builtin_inff(),-__builtin_inff(),-__builtin_inff());
    for (int j=0;j<NK;++j){
      int q = pbl + idx_s[pl*NK + j];
      float4 g = ld4(xcat + (size_t)q*(2*DOUT) + DOUT + c);
      mv.x = fmaxf(mv.x, g.x); mv.y = fmaxf(mv.y, g.y);
      mv.z = fmaxf(mv.z, g.z); mv.w = fmaxf(mv.w, g.w);
    }
    float4 v;
    v.x = fmaxf(z.x + b4.x - ys.x + mv.x, 0.f);
    v.y = fmaxf(z.y + b4.y - ys.y + mv.y, 0.f);
    v.z = fmaxf(z.z + b4.z - ys.z + mv.z, 0.f);
    v.w = fmaxf(z.w + b4.w - ys.w + mv.w, 0.f);
    st4(hout + (size_t)(p0 + pl)*DOUT + c, v);
    fsum.x += v.x; fsum.y += v.y; fsum.z += v.z; fsum.w += v.w;
    ss += v.x*v.x + v.y*v.y + v.z*v.z + v.w*v.w;
  }
  st4(&red[pr*DOUT + c], fsum);
#pragma unroll
  for (int off=32; off; off>>=1) ss += __shfl_xor(ss, off, 64);
  if ((threadIdx.x&63)==0) ssp[threadIdx.x>>6] = ss;
  __syncthreads();
  for (int o=threadIdx.x; o<DOUT; o+=256){
    float s = 0.f;
#pragma unroll
    for (int r=0;r<ROWS;++r) s += red[r*DOUT + o];
    atomicAdd(stats + o, s);
  }
  if (threadIdx.x==0) atomicAdd(stats+256, ssp[0]+ssp[1]+ssp[2]+ssp[3]);
}

// ---------------- top-k selection (wave per row) ----------------
__global__ __launch_bounds__(256) void k_topk(const float* __restrict__ dist,
    int* __restrict__ idx, int b0){
  int wave = threadIdx.x>>6, lane = threadIdx.x&63;
  int rowg = blockIdx.x*4 + wave;          // = bz*NP + n
  int bz = rowg >> 10, n = rowg & 1023;
  const float* dr = dist + (size_t)rowg * NP;
  float dv[16];
#pragma unroll
  for (int t=0;t<16;++t) dv[t] = dr[lane + 64*t];
  int* out = idx + ((size_t)(b0+bz)*NP + n)*NK;
  for (int kk=0; kk<NK; ++kk){
    float bvv = dv[0]; int bm = lane;
#pragma unroll
    for (int t=1;t<16;++t){
      int m = lane + 64*t;
      if (dv[t] < bvv){ bvv = dv[t]; bm = m; }   // ascending m, strict < => lowest idx on tie
    }
#pragma unroll
    for (int off=32; off; off>>=1){
      float ov = __shfl_xor(bvv, off, 64);
      int om = __shfl_xor(bm, off, 64);
      if (ov < bvv || (ov == bvv && om < bm)){ bvv = ov; bm = om; }
    }
    if (lane == 0) out[kk] = bm;
    int tsel = bm>>6, lsel = bm&63;
#pragma unroll
    for (int t=0;t<16;++t)
      if (t == tsel && lane == lsel) dv[t] = __builtin_inff();   // static indexing
  }
}

// ---------------- edge conv layer 1 (din=2, dout=64) ----------------
__global__ __launch_bounds__(256) void k_edge1(const float* __restrict__ x,
    const int* __restrict__ idx, const float* __restrict__ W,
    const float* __restrict__ bias, float* __restrict__ hout,
    float* __restrict__ stats){
  __shared__ int idx_s[4][NK];
  __shared__ float red[4][64];
  int p = threadIdx.x>>6, o = threadIdx.x&63;
  int p0 = blockIdx.x*4;
  int b = p0 >> 10;
  int pl0 = p0 & 1023;
  const float* xb = x + ((size_t)b<<10)*2;
  if (threadIdx.x < 4*NK) idx_s[threadIdx.x/NK][threadIdx.x%NK] = idx[(size_t)p0*NK + threadIdx.x];
  __syncthreads();
  float w0=W[o], w1=W[64+o], w2=W[128+o], w3=W[192+o];
  float2 xi = ld2(xb + (size_t)(pl0+p)*2);
  float common = xi.x*w0 + xi.y*w1 + bias[o];
  float mv = -__builtin_inff();
  for (int j=0;j<NK;++j){
    float2 xj = ld2(xb + (size_t)idx_s[p][j]*2);
    mv = fmaxf(mv, (xj.x-xi.x)*w2 + (xj.y-xi.y)*w3);
  }
  float v = fmaxf(common + mv, 0.f);
  hout[(size_t)(p0+p)*64 + o] = v;
  red[p][o] = v;
  float ss = v*v;
#pragma unroll
  for (int off=32; off; off>>=1) ss += __shfl_xor(ss, off, 64);
  if ((threadIdx.x&63)==0) atomicAdd(stats+256, ss);
  __syncthreads();
  if (threadIdx.x < 64){
    float s = red[0][o]+red[1][o]+red[2][o]+red[3][o];
    atomicAdd(stats + o, s);
  }
}

// ---------------- finalize PairNorm stats ----------------
__global__ __launch_bounds__(256) void k_finalize(float* stats, int dout){
  __shared__ float part[4];
  int o = threadIdx.x;
  float m = (o < dout) ? stats[o] * (1.f/BN) : 0.f;
  stats[320+o] = m;                    // mu
  float p = m*m;
#pragma unroll
  for (int off=32; off; off>>=1) p += __shfl_xor(p, off, 64);
  if ((o&63)==0) part[o>>6] = p;
  __syncthreads();
  if (o==0){
    float s = part[0]+part[1]+part[2]+part[3];
    float msn = stats[256]*(1.f/BN) - s;
    stats[576] = 1.f / sqrtf(1e-5f + msn);
  }
}

// ---------------- normalize in place + next-layer sq ----------------
template<int DOUT>
__global__ __launch_bounds__(256) void k_norm(float* __restrict__ h,
    const float* __restrict__ stats, float* __restrict__ sq){
  __shared__ float part[4];
  int row = blockIdx.x, o = threadIdx.x;
  float inv = stats[576];
  float v = (h[(size_t)row*DOUT + o] - stats[320+o]) * inv;
  h[(size_t)row*DOUT + o] = v;
  float s = v*v;
#pragma unroll
  for (int off=32; off; off>>=1) s += __shfl_xor(s, off, 64);
  if constexpr (DOUT==64){
    if (o==0) sq[row] = s;
  } else {
    if ((o&63)==0) part[o>>6] = s;
    __syncthreads();
    if (o==0){ float t=0.f; for (int w2=0; w2<DOUT/64; ++w2) t += part[w2]; sq[row] = t; }
  }
}

// ---------------- global max pool (partial) ----------------
__global__ __launch_bounds__(256) void k_pool1(const float* __restrict__ h, float* __restrict__ gpart){
  int b = blockIdx.x, c = blockIdx.y, o = threadIdx.x;
  const float* hp = h + ((size_t)b*NP + c*128)*256 + o;
  float m = -__builtin_inff();
  for (int n=0;n<128;++n) m = fmaxf(m, hp[(size_t)n*256]);
  gpart[((size_t)c*NB + b)*256 + o] = m;
}

// ---------------- pool finish + MLP head ----------------
__global__ __launch_bounds__(256) void k_head(const float* __restrict__ gpart,
    const float* __restrict__ Wl1, const float* __restrict__ bl1,
    const float* __restrict__ Wl2, const float* __restrict__ bl2,
    float* __restrict__ out){
  __shared__ float g_s[256];
  __shared__ float h_s[64];
  int b = blockIdx.x, t = threadIdx.x;
  float m = -__builtin_inff();
  for (int c=0;c<8;++c) m = fmaxf(m, gpart[((size_t)c*NB + b)*256 + t]);
  g_s[t] = m;
  __syncthreads();
  if (t < 64){
    float a = bl1[t];
    for (int k=0;k<256;++k) a += g_s[k]*Wl1[(size_t)k*64 + t];
    h_s[t] = fmaxf(a, 0.f);
  }
  __syncthreads();
  if (t < 2){
    float a = bl2[t];
    for (int i=0;i<64;++i) a += h_s[i]*Wl2[(size_t)i*2 + t];
    out[(size_t)b*2 + t] = a;
  }
}

extern "C" void kernel_launch(void* const* d_in, const int* in_sizes, int n_in,
                              void* d_out, int out_size, void* d_ws, size_t ws_size,
                              hipStream_t stream){
  (void)in_sizes; (void)n_in; (void)out_size; (void)ws_size;
  const float* pos = (const float*)d_in[0];
  const float* W1  = (const float*)d_in[1];
  const float* b1  = (const float*)d_in[2];
  const float* W2  = (const float*)d_in[3];
  const float* b2  = (const float*)d_in[4];
  const float* W3  = (const float*)d_in[5];
  const float* b3  = (const float*)d_in[6];
  const float* Wl1 = (const float*)d_in[7];
  const float* bl1 = (const float*)d_in[8];
  const float* Wl2 = (const float*)d_in[9];
  const float* bl2 = (const float*)d_in[10];
  float* outp = (float*)d_out;

  // dynamic-LDS opt-in for the 128 KB kernels (idempotent host-side calls)
  (void)hipFuncSetAttribute((const void*)k_dist<128>,      hipFuncAttributeMaxDynamicSharedMemorySize, 131072);
  (void)hipFuncSetAttribute((const void*)k_gemm<128,256>,  hipFuncAttributeMaxDynamicSharedMemorySize, 131072);
  (void)hipFuncSetAttribute((const void*)k_dist<64>,       hipFuncAttributeMaxDynamicSharedMemorySize, 65536);
  (void)hipFuncSetAttribute((const void*)k_gemm<64,128>,   hipFuncAttributeMaxDynamicSharedMemorySize, 65536);

  char* w = (char*)d_ws;
  size_t off = 0;
  auto take = [&](size_t bytes)->char*{ char* p = w + off; off += (bytes + 255) & ~(size_t)255; return p; };
  float* sq    = (float*)take((size_t)BN*4);
  int*   idx   = (int*)  take((size_t)BN*NK*4);
  float* x1    = (float*)take((size_t)BN*64*4);
  float* x2    = (float*)take((size_t)BN*128*4);
  float* x3    = (float*)take((size_t)BN*256*4);
  float* stats = (float*)take(4096);
  float* gpart = (float*)take((size_t)8*NB*256*4);
  float* big   = (float*)take((size_t)NBCH*NP*NP*4);   // dist chunk / xcat chunk (33.55 MB); total ~94 MB
  float* dist  = big;
  float* xcat  = big;

  dim3 gdist(NP/128, NP/128, NBCH);

  // ---- layer 1 ----
  k_sq_pos<<<BN/256, 256, 0, stream>>>(pos, sq);
  for (int c=0;c<NB/NBCH;++c){
    k_dist2<<<gdist, 256, 0, stream>>>(pos, sq, dist, c*NBCH);
    k_topk<<<NBCH*NP/4, 256, 0, stream>>>(dist, idx, c*NBCH);
  }
  hipMemsetAsync(stats, 0, 4096, stream);
  k_edge1<<<BN/4, 256, 0, stream>>>(pos, idx, W1, b1, x1, stats);
  k_finalize<<<1, 256, 0, stream>>>(stats, 64);
  k_norm<64><<<BN, 64, 0, stream>>>(x1, stats, sq);

  // ---- layer 2 ----
  for (int c=0;c<NB/NBCH;++c){
    k_dist<64><<<gdist, 256, 65536, stream>>>(x1, sq, dist, c*NBCH);
    k_topk<<<NBCH*NP/4, 256, 0, stream>>>(dist, idx, c*NBCH);
  }
  hipMemsetAsync(stats, 0, 4096, stream);
  k_gemm<64,128><<<dim3(BN/128, 2), 256, 65536, stream>>>(x1, W2, xcat, 0);
  k_gmax<128><<<BN/32, 256, 0, stream>>>(xcat, idx, b2, x2, stats, 0);
  k_finalize<<<1, 256, 0, stream>>>(stats, 128);
  k_norm<128><<<BN, 128, 0, stream>>>(x2, stats, sq);

  // ---- layer 3 ----
  for (int c=0;c<NB/NBCH;++c){
    k_dist<128><<<gdist, 256, 131072, stream>>>(x2, sq, dist, c*NBCH);
    k_topk<<<NBCH*NP/4, 256, 0, stream>>>(dist, idx, c*NBCH);
  }
  hipMemsetAsync(stats, 0, 4096, stream);
  for (int h=0; h<2; ++h){
    int m_base = h * (BN/2);
    k_gemm<128,256><<<dim3(BN/2/128, 4), 256, 131072, stream>>>(x2, W3, xcat, m_base);
    k_gmax<256><<<BN/2/32, 256, 0, stream>>>(xcat, idx, b3, x3, stats, m_base);
  }
  k_finalize<<<1, 256, 0, stream>>>(stats, 256);
  k_norm<256><<<BN, 256, 0, stream>>>(x3, stats, sq);

  // ---- pool + head ----
  k_pool1<<<dim3(NB, 8), 256, 0, stream>>>(x3, gpart);
  k_head<<<NB, 256, 0, stream>>>(gpart, Wl1, bl1, Wl2, bl2, outp);
}

// Round 4
// 1022.908 us; speedup vs baseline: 4.7067x; 1.3726x over previous
//
#include <hip/hip_runtime.h>
#include <math.h>

constexpr int NB = 32;      // batches
constexpr int NP = 1024;    // points per batch
constexpr int NK = 10;      // k nearest (includes self)
constexpr int BN = NB * NP;
constexpr int NBCH = 8;     // batches per dist chunk
constexpr int NSLOT = 1024; // partial-reduction slots for PairNorm stats

__device__ __forceinline__ float4 ld4(const float* p){ return *reinterpret_cast<const float4*>(p); }
__device__ __forceinline__ float2 ld2(const float* p){ return *reinterpret_cast<const float2*>(p); }
__device__ __forceinline__ void st4(float* p, float4 v){ *reinterpret_cast<float4*>(p) = v; }

// ---------------- sq norms of pos ----------------
__global__ __launch_bounds__(256) void k_sq_pos(const float* __restrict__ x, float* __restrict__ sq){
  int i = blockIdx.x*256 + threadIdx.x;
  float2 v = ld2(x + (size_t)2*i);
  sq[i] = v.x*v.x + v.y*v.y;
}

// ---------------- dist matrix, DIN=2 (layer 1) ----------------
__global__ __launch_bounds__(256) void k_dist2(const float* __restrict__ x,
    const float* __restrict__ sq, float* __restrict__ dist, int b0){
  int bz = blockIdx.z;
  int b = b0 + bz;
  int n0 = blockIdx.x*128, m0 = blockIdx.y*128;
  int ry = threadIdx.x>>4, rx = threadIdx.x&15;
  const float* xb = x + (size_t)b*NP*2;
  const float* sqb = sq + (size_t)b*NP;
  float2 av[8], bv[8]; float sn[8], sm[8];
#pragma unroll
  for (int k=0;k<8;++k){
    av[k] = ld2(xb + (size_t)(n0+ry*8+k)*2);
    bv[k] = ld2(xb + (size_t)(m0+rx*8+k)*2);
    sn[k] = sqb[n0+ry*8+k];
    sm[k] = sqb[m0+rx*8+k];
  }
  float* dbase = dist + ((size_t)bz*NP + n0 + ry*8)*NP + m0 + rx*8;
#pragma unroll
  for (int k=0;k<8;++k){
    float r[8];
#pragma unroll
    for (int l=0;l<8;++l){
      float dot = av[k].x*bv[l].x + av[k].y*bv[l].y;
      r[l] = (sn[k] + sm[l]) - 2.f*dot;
    }
    st4(dbase + (size_t)k*NP,     make_float4(r[0],r[1],r[2],r[3]));
    st4(dbase + (size_t)k*NP + 4, make_float4(r[4],r[5],r[6],r[7]));
  }
}

// ---------------- dist matrix, DIN in {64,128}: full-K LDS, 1 barrier ----------------
template<int DIN>
__global__ __launch_bounds__(256) void k_dist(const float* __restrict__ x,
    const float* __restrict__ sq, float* __restrict__ dist, int b0){
  constexpr int K4 = DIN/4, MASK = K4-1;
  extern __shared__ float4 smem[];
  float4* as4 = smem;            // 128*K4
  float4* bs4 = smem + 128*K4;   // 128*K4
  int bz = blockIdx.z;
  int b = b0 + bz;
  int n0 = blockIdx.x*128, m0 = blockIdx.y*128;
  int ry = threadIdx.x>>4, rx = threadIdx.x&15;
  const float* xb = x + (size_t)b*NP*DIN;
  for (int u=threadIdx.x; u<128*K4; u+=256){
    int r = u / K4, c = u % K4;
    int sw = r*K4 + ((c + (r>>3)) & MASK);
    as4[sw] = ld4(xb + (size_t)(n0+r)*DIN + 4*c);
    bs4[sw] = ld4(xb + (size_t)(m0+r)*DIN + 4*c);
  }
  __syncthreads();
  float acc[8][8];
#pragma unroll
  for (int k=0;k<8;++k)
#pragma unroll
    for (int l=0;l<8;++l) acc[k][l] = 0.f;
#pragma unroll 2
  for (int d4=0; d4<K4; ++d4){
    float4 a_[8], b_[8];
#pragma unroll
    for (int k=0;k<8;++k) a_[k] = as4[(ry*8+k)*K4 + ((d4 + ry) & MASK)];
#pragma unroll
    for (int l=0;l<8;++l) b_[l] = bs4[(rx*8+l)*K4 + ((d4 + rx) & MASK)];
#pragma unroll
    for (int k=0;k<8;++k)
#pragma unroll
      for (int l=0;l<8;++l)
        acc[k][l] += a_[k].x*b_[l].x + a_[k].y*b_[l].y + a_[k].z*b_[l].z + a_[k].w*b_[l].w;
  }
  const float* sqb = sq + (size_t)b*NP;
  float sn[8], sm[8];
#pragma unroll
  for (int k=0;k<8;++k){ sn[k] = sqb[n0+ry*8+k]; sm[k] = sqb[m0+rx*8+k]; }
  float* dbase = dist + ((size_t)bz*NP + n0 + ry*8)*NP + m0 + rx*8;
#pragma unroll
  for (int k=0;k<8;++k){
    float r[8];
#pragma unroll
    for (int l=0;l<8;++l) r[l] = (sn[k]+sm[l]) - 2.f*acc[k][l];
    st4(dbase + (size_t)k*NP,     make_float4(r[0],r[1],r[2],r[3]));
    st4(dbase + (size_t)k*NP + 4, make_float4(r[4],r[5],r[6],r[7]));
  }
}

// ---------------- GEMM: xcat = x @ [Wtop | Wbot], full-K LDS ----------------
template<int DIN, int DOUT>
__global__ __launch_bounds__(256) void k_gemm(const float* __restrict__ x,
    const float* __restrict__ W, float* __restrict__ xcat, int m_base){
  constexpr int K4 = DIN/4, MASK = K4-1;
  extern __shared__ float4 smem[];
  float4* as4 = smem;            // 128*K4
  float4* bs4 = smem + 128*K4;   // 128*K4
  int m0 = blockIdx.x*128;                 // local row tile
  int nc = blockIdx.y*128;                 // output col tile in [0, 2*DOUT)
  bool isBot = (nc >= DOUT);
  int bcol = isBot ? nc - DOUT : nc;
  const float* B = W + (isBot ? (size_t)DIN*DOUT : 0);
  const float* xg = x + (size_t)(m_base + m0)*DIN;
  for (int u=threadIdx.x; u<128*K4; u+=256){
    int r = u / K4, c = u % K4;
    as4[r*K4 + ((c + (r>>3)) & MASK)] = ld4(xg + (size_t)r*DIN + 4*c);
  }
  float* bsf = reinterpret_cast<float*>(bs4);
  for (int u=threadIdx.x; u<DIN*128; u+=256){
    int k = u >> 7, n = u & 127;
    bsf[(n*K4 + (((k>>2) + (n>>3)) & MASK))*4 + (k&3)] = B[(size_t)k*DOUT + bcol + n];
  }
  __syncthreads();
  int ry = threadIdx.x>>4, rx = threadIdx.x&15;
  float acc[8][8];
#pragma unroll
  for (int k=0;k<8;++k)
#pragma unroll
    for (int l=0;l<8;++l) acc[k][l] = 0.f;
#pragma unroll 2
  for (int d4=0; d4<K4; ++d4){
    float4 a_[8], b_[8];
#pragma unroll
    for (int k=0;k<8;++k) a_[k] = as4[(ry*8+k)*K4 + ((d4 + ry) & MASK)];
#pragma unroll
    for (int l=0;l<8;++l) b_[l] = bs4[(rx*8+l)*K4 + ((d4 + rx) & MASK)];
#pragma unroll
    for (int k=0;k<8;++k)
#pragma unroll
      for (int l=0;l<8;++l)
        acc[k][l] += a_[k].x*b_[l].x + a_[k].y*b_[l].y + a_[k].z*b_[l].z + a_[k].w*b_[l].w;
  }
  float* outb = xcat + (size_t)(m0 + ry*8)*(2*DOUT) + nc + rx*8;
#pragma unroll
  for (int k=0;k<8;++k){
    st4(outb + (size_t)k*(2*DOUT),     make_float4(acc[k][0],acc[k][1],acc[k][2],acc[k][3]));
    st4(outb + (size_t)k*(2*DOUT) + 4, make_float4(acc[k][4],acc[k][5],acc[k][6],acc[k][7]));
  }
}

// ---------------- gather-max epilogue: h = relu(z + b - y_self + max_j y_j) ----------------
// Stats via per-block partials into spart[f*NSLOT + slot] (feature-major), no atomics.
template<int DOUT>
__global__ __launch_bounds__(256) void k_gmax(const float* __restrict__ xcat,
    const int* __restrict__ idx, const float* __restrict__ bias,
    float* __restrict__ hout, float* __restrict__ spart, int p_base, int slot_base){
  constexpr int TP = DOUT/4;        // threads per point
  constexpr int ROWS = 256/TP;      // points in flight
  constexpr int PPT = 32/ROWS;      // points per thread
  __shared__ int idx_s[32*NK];
  __shared__ float red[1024];       // ROWS*DOUT == 1024 floats
  __shared__ float ssp[4];
  int c4 = threadIdx.x % TP, pr = threadIdx.x / TP;
  int c = 4*c4;
  int p0 = blockIdx.x*32 + p_base;          // global first point of block
  for (int t=threadIdx.x; t<32*NK; t+=256) idx_s[t] = idx[(size_t)p0*NK + t];
  __syncthreads();
  float4 b4 = ld4(bias + c);
  float4 fsum = make_float4(0.f,0.f,0.f,0.f);
  float ss = 0.f;
  int pbl = (((p0 - p_base) >> 10) << 10);  // local batch base row
#pragma unroll
  for (int t=0; t<PPT; ++t){
    int pl = pr + t*ROWS;
    int lrow = (p0 - p_base) + pl;
    const float* row = xcat + (size_t)lrow*(2*DOUT);
    float4 z = ld4(row + c), ys = ld4(row + DOUT + c);
    float4 mv = make_float4(-__builtin_inff(),-__builtin_inff(),-__builtin_inff(),-__builtin_inff());
    for (int j=0;j<NK;++j){
      int q = pbl + idx_s[pl*NK + j];
      float4 g = ld4(xcat + (size_t)q*(2*DOUT) + DOUT + c);
      mv.x = fmaxf(mv.x, g.x); mv.y = fmaxf(mv.y, g.y);
      mv.z = fmaxf(mv.z, g.z); mv.w = fmaxf(mv.w, g.w);
    }
    float4 v;
    v.x = fmaxf(z.x + b4.x - ys.x + mv.x, 0.f);
    v.y = fmaxf(z.y + b4.y - ys.y + mv.y, 0.f);
    v.z = fmaxf(z.z + b4.z - ys.z + mv.z, 0.f);
    v.w = fmaxf(z.w + b4.w - ys.w + mv.w, 0.f);
    st4(hout + (size_t)(p0 + pl)*DOUT + c, v);
    fsum.x += v.x; fsum.y += v.y; fsum.z += v.z; fsum.w += v.w;
    ss += v.x*v.x + v.y*v.y + v.z*v.z + v.w*v.w;
  }
  st4(&red[pr*DOUT + c], fsum);
#pragma unroll
  for (int off=32; off; off>>=1) ss += __shfl_xor(ss, off, 64);
  if ((threadIdx.x&63)==0) ssp[threadIdx.x>>6] = ss;
  __syncthreads();
  int slot = slot_base + blockIdx.x;
  for (int o=threadIdx.x; o<DOUT; o+=256){
    float s = 0.f;
#pragma unroll
    for (int r=0;r<ROWS;++r) s += red[r*DOUT + o];
    spart[(size_t)o*NSLOT + slot] = s;
  }
  if (threadIdx.x==0) spart[(size_t)DOUT*NSLOT + slot] = ssp[0]+ssp[1]+ssp[2]+ssp[3];
}

// ---------------- top-k selection (wave per row) ----------------
__global__ __launch_bounds__(256) void k_topk(const float* __restrict__ dist,
    int* __restrict__ idx, int b0){
  int wave = threadIdx.x>>6, lane = threadIdx.x&63;
  int rowg = blockIdx.x*4 + wave;          // = bz*NP + n
  int bz = rowg >> 10, n = rowg & 1023;
  const float* dr = dist + (size_t)rowg * NP;
  float dv[16];
#pragma unroll
  for (int t=0;t<16;++t) dv[t] = dr[lane + 64*t];
  int* out = idx + ((size_t)(b0+bz)*NP + n)*NK;
  for (int kk=0; kk<NK; ++kk){
    float bvv = dv[0]; int bm = lane;
#pragma unroll
    for (int t=1;t<16;++t){
      int m = lane + 64*t;
      if (dv[t] < bvv){ bvv = dv[t]; bm = m; }   // ascending m, strict < => lowest idx on tie
    }
#pragma unroll
    for (int off=32; off; off>>=1){
      float ov = __shfl_xor(bvv, off, 64);
      int om = __shfl_xor(bm, off, 64);
      if (ov < bvv || (ov == bvv && om < bm)){ bvv = ov; bm = om; }
    }
    if (lane == 0) out[kk] = bm;
    int tsel = bm>>6, lsel = bm&63;
#pragma unroll
    for (int t=0;t<16;++t)
      if (t == tsel && lane == lsel) dv[t] = __builtin_inff();   // static indexing
  }
}

// ---------------- edge conv layer 1 (din=2, dout=64) ----------------
// 32 points/block (1024 blocks); wave w handles 8 points; lane = feature. No atomics.
__global__ __launch_bounds__(256) void k_edge1(const float* __restrict__ x,
    const int* __restrict__ idx, const float* __restrict__ W,
    const float* __restrict__ bias, float* __restrict__ hout,
    float* __restrict__ spart){
  __shared__ int idx_s[32*NK];
  __shared__ float red[4][64];
  __shared__ float ssw[4];
  int lane = threadIdx.x & 63, wv = threadIdx.x >> 6;
  int p0 = blockIdx.x * 32;
  int b = p0 >> 10;
  int pl0 = p0 & 1023;
  const float* xb = x + ((size_t)b<<10)*2;
  for (int t=threadIdx.x; t<32*NK; t+=256) idx_s[t] = idx[(size_t)p0*NK + t];
  __syncthreads();
  float w0=W[lane], w1=W[64+lane], w2=W[128+lane], w3=W[192+lane];
  float bi = bias[lane];
  float fsum = 0.f, ss = 0.f;
#pragma unroll
  for (int t=0;t<8;++t){
    int pl = wv*8 + t;
    float2 xi = ld2(xb + (size_t)(pl0+pl)*2);
    float common = xi.x*w0 + xi.y*w1 + bi;
    float mv = -__builtin_inff();
    for (int j=0;j<NK;++j){
      float2 xj = ld2(xb + (size_t)idx_s[pl*NK+j]*2);
      mv = fmaxf(mv, (xj.x-xi.x)*w2 + (xj.y-xi.y)*w3);
    }
    float v = fmaxf(common + mv, 0.f);
    hout[(size_t)(p0+pl)*64 + lane] = v;
    fsum += v; ss += v*v;
  }
  red[wv][lane] = fsum;
#pragma unroll
  for (int off=32; off; off>>=1) ss += __shfl_xor(ss, off, 64);
  if (lane==0) ssw[wv] = ss;
  __syncthreads();
  if (threadIdx.x < 64){
    float s = red[0][lane]+red[1][lane]+red[2][lane]+red[3][lane];
    spart[(size_t)lane*NSLOT + blockIdx.x] = s;
  }
  if (threadIdx.x==0) spart[(size_t)64*NSLOT + blockIdx.x] = ssw[0]+ssw[1]+ssw[2]+ssw[3];
}

// ---------------- finalize PairNorm stats from partials ----------------
template<int DOUT>
__global__ __launch_bounds__(256) void k_finalize2(const float* __restrict__ spart,
    float* __restrict__ stats){
  __shared__ float part[4];
  __shared__ float ssh;
  float musq = 0.f;
  for (int f = threadIdx.x; f <= DOUT; f += 256){
    const float* row = spart + (size_t)f*NSLOT;
    float4 a = make_float4(0.f,0.f,0.f,0.f);
    for (int s=0; s<NSLOT; s+=4){
      float4 v = ld4(row + s);
      a.x += v.x; a.y += v.y; a.z += v.z; a.w += v.w;
    }
    float s = (a.x + a.y) + (a.z + a.w);
    if (f < DOUT){
      float m = s * (1.f/BN);
      stats[320+f] = m;
      musq += m*m;
    } else {
      ssh = s;
    }
  }
#pragma unroll
  for (int off=32; off; off>>=1) musq += __shfl_xor(musq, off, 64);
  if ((threadIdx.x&63)==0) part[threadIdx.x>>6] = musq;
  __syncthreads();
  if (threadIdx.x==0){
    float mu2 = part[0]+part[1]+part[2]+part[3];
    float msn = ssh*(1.f/BN) - mu2;
    stats[576] = 1.f / sqrtf(1e-5f + msn);
  }
}

// ---------------- normalize in place + next-layer sq (wave per row) ----------------
template<int DOUT>
__global__ __launch_bounds__(256) void k_norm(float* __restrict__ h,
    const float* __restrict__ stats, float* __restrict__ sq){
  int lane = threadIdx.x&63, wv = threadIdx.x>>6;
  int row = blockIdx.x*4 + wv;
  float inv = stats[576];
  const float* mu = stats + 320;
  float* hr = h + (size_t)row*DOUT;
  float s = 0.f;
  if constexpr (DOUT == 64){
    float v = (hr[lane] - mu[lane]) * inv;
    hr[lane] = v;
    s = v*v;
  } else if constexpr (DOUT == 128){
    float2 x2 = ld2(hr + 2*lane), m2 = ld2(mu + 2*lane);
    float a = (x2.x - m2.x)*inv, b = (x2.y - m2.y)*inv;
    *reinterpret_cast<float2*>(hr + 2*lane) = make_float2(a,b);
    s = a*a + b*b;
  } else {
    float4 x4 = ld4(hr + 4*lane), m4 = ld4(mu + 4*lane);
    float4 v;
    v.x = (x4.x-m4.x)*inv; v.y = (x4.y-m4.y)*inv;
    v.z = (x4.z-m4.z)*inv; v.w = (x4.w-m4.w)*inv;
    st4(hr + 4*lane, v);
    s = v.x*v.x + v.y*v.y + v.z*v.z + v.w*v.w;
  }
#pragma unroll
  for (int off=32; off; off>>=1) s += __shfl_xor(s, off, 64);
  if (lane==0) sq[row] = s;
}

// ---------------- global max pool (partial) ----------------
__global__ __launch_bounds__(256) void k_pool1(const float* __restrict__ h, float* __restrict__ gpart){
  int b = blockIdx.x, c = blockIdx.y, o = threadIdx.x;
  const float* hp = h + ((size_t)b*NP + c*128)*256 + o;
  float m = -__builtin_inff();
  for (int n=0;n<128;++n) m = fmaxf(m, hp[(size_t)n*256]);
  gpart[((size_t)c*NB + b)*256 + o] = m;
}

// ---------------- pool finish + MLP head ----------------
__global__ __launch_bounds__(256) void k_head(const float* __restrict__ gpart,
    const float* __restrict__ Wl1, const float* __restrict__ bl1,
    const float* __restrict__ Wl2, const float* __restrict__ bl2,
    float* __restrict__ out){
  __shared__ float g_s[256];
  __shared__ float h_s[64];
  int b = blockIdx.x, t = threadIdx.x;
  float m = -__builtin_inff();
  for (int c=0;c<8;++c) m = fmaxf(m, gpart[((size_t)c*NB + b)*256 + t]);
  g_s[t] = m;
  __syncthreads();
  if (t < 64){
    float a = bl1[t];
    for (int k=0;k<256;++k) a += g_s[k]*Wl1[(size_t)k*64 + t];
    h_s[t] = fmaxf(a, 0.f);
  }
  __syncthreads();
  if (t < 2){
    float a = bl2[t];
    for (int i=0;i<64;++i) a += h_s[i]*Wl2[(size_t)i*2 + t];
    out[(size_t)b*2 + t] = a;
  }
}

extern "C" void kernel_launch(void* const* d_in, const int* in_sizes, int n_in,
                              void* d_out, int out_size, void* d_ws, size_t ws_size,
                              hipStream_t stream){
  (void)in_sizes; (void)n_in; (void)out_size; (void)ws_size;
  const float* pos = (const float*)d_in[0];
  const float* W1  = (const float*)d_in[1];
  const float* b1  = (const float*)d_in[2];
  const float* W2  = (const float*)d_in[3];
  const float* b2  = (const float*)d_in[4];
  const float* W3  = (const float*)d_in[5];
  const float* b3  = (const float*)d_in[6];
  const float* Wl1 = (const float*)d_in[7];
  const float* bl1 = (const float*)d_in[8];
  const float* Wl2 = (const float*)d_in[9];
  const float* bl2 = (const float*)d_in[10];
  float* outp = (float*)d_out;

  (void)hipFuncSetAttribute((const void*)k_dist<128>,      hipFuncAttributeMaxDynamicSharedMemorySize, 131072);
  (void)hipFuncSetAttribute((const void*)k_gemm<128,256>,  hipFuncAttributeMaxDynamicSharedMemorySize, 131072);
  (void)hipFuncSetAttribute((const void*)k_dist<64>,       hipFuncAttributeMaxDynamicSharedMemorySize, 65536);
  (void)hipFuncSetAttribute((const void*)k_gemm<64,128>,   hipFuncAttributeMaxDynamicSharedMemorySize, 65536);

  char* w = (char*)d_ws;
  size_t off = 0;
  auto take = [&](size_t bytes)->char*{ char* p = w + off; off += (bytes + 255) & ~(size_t)255; return p; };
  float* sq    = (float*)take((size_t)BN*4);
  int*   idx   = (int*)  take((size_t)BN*NK*4);
  float* x1    = (float*)take((size_t)BN*64*4);
  float* x2    = (float*)take((size_t)BN*128*4);
  float* x3    = (float*)take((size_t)BN*256*4);
  float* stats = (float*)take(4096);
  float* spart = (float*)take((size_t)257*NSLOT*4);    // feature-major partials
  float* gpart = (float*)take((size_t)8*NB*256*4);
  float* big   = (float*)take((size_t)NBCH*NP*NP*4);   // dist chunk / xcat chunk (33.55 MB)
  float* dist  = big;
  float* xcat  = big;

  dim3 gdist(NP/128, NP/128, NBCH);

  // ---- layer 1 ----
  k_sq_pos<<<BN/256, 256, 0, stream>>>(pos, sq);
  for (int c=0;c<NB/NBCH;++c){
    k_dist2<<<gdist, 256, 0, stream>>>(pos, sq, dist, c*NBCH);
    k_topk<<<NBCH*NP/4, 256, 0, stream>>>(dist, idx, c*NBCH);
  }
  k_edge1<<<NSLOT, 256, 0, stream>>>(pos, idx, W1, b1, x1, spart);
  k_finalize2<64><<<1, 256, 0, stream>>>(spart, stats);
  k_norm<64><<<BN/4, 256, 0, stream>>>(x1, stats, sq);

  // ---- layer 2 ----
  for (int c=0;c<NB/NBCH;++c){
    k_dist<64><<<gdist, 256, 65536, stream>>>(x1, sq, dist, c*NBCH);
    k_topk<<<NBCH*NP/4, 256, 0, stream>>>(dist, idx, c*NBCH);
  }
  k_gemm<64,128><<<dim3(BN/128, 2), 256, 65536, stream>>>(x1, W2, xcat, 0);
  k_gmax<128><<<BN/32, 256, 0, stream>>>(xcat, idx, b2, x2, spart, 0, 0);
  k_finalize2<128><<<1, 256, 0, stream>>>(spart, stats);
  k_norm<128><<<BN/4, 256, 0, stream>>>(x2, stats, sq);

  // ---- layer 3 ----
  for (int c=0;c<NB/NBCH;++c){
    k_dist<128><<<gdist, 256, 131072, stream>>>(x2, sq, dist, c*NBCH);
    k_topk<<<NBCH*NP/4, 256, 0, stream>>>(dist, idx, c*NBCH);
  }
  for (int h=0; h<2; ++h){
    int m_base = h * (BN/2);
    k_gemm<128,256><<<dim3(BN/2/128, 4), 256, 131072, stream>>>(x2, W3, xcat, m_base);
    k_gmax<256><<<BN/2/32, 256, 0, stream>>>(xcat, idx, b3, x3, spart, m_base, h*(BN/2/32));
  }
  k_finalize2<256><<<1, 256, 0, stream>>>(spart, stats);
  k_norm<256><<<BN/4, 256, 0, stream>>>(x3, stats, sq);

  // ---- pool + head ----
  k_pool1<<<dim3(NB, 8), 256, 0, stream>>>(x3, gpart);
  k_head<<<NB, 256, 0, stream>>>(gpart, Wl1, bl1, Wl2, bl2, outp);
}